// Round 11
// baseline (278.812 us; speedup 1.0000x reference)
//
#include <hip/hip_runtime.h>
#include <hip/hip_bf16.h>

#define DIM 1024
#define HEADS 16
#define DH 64
#define SEQ 2048
#define BATCH 4
#define ROWS (BATCH * SEQ)   // 8192
#define NQKV (3 * DIM)       // 3072

typedef __attribute__((ext_vector_type(8))) __bf16 bf16x8;
typedef __attribute__((ext_vector_type(4))) __bf16 bf16x4;
typedef __attribute__((ext_vector_type(4))) float f32x4;

__device__ inline void gload16(const void* g, void* l) {
  __builtin_amdgcn_global_load_lds(
      (const __attribute__((address_space(1))) void*)g,
      (__attribute__((address_space(3))) void*)l, 16, 0, 0);
}

__device__ inline float fast_exp2(float x) {
#if __has_builtin(__builtin_amdgcn_exp2f)
  return __builtin_amdgcn_exp2f(x);  // raw v_exp_f32, no denorm guard
#else
  return exp2f(x);
#endif
}

// ------- fused LayerNorm (blocks 0..8191) + weight transpose (8192..12287) ----
__global__ __launch_bounds__(256) void ln_tc(
    const float* __restrict__ x, const float* __restrict__ gamma,
    const float* __restrict__ beta, __bf16* __restrict__ xnb,
    const float* __restrict__ wq, const float* __restrict__ wo,
    __bf16* __restrict__ qT, __bf16* __restrict__ oT) {
  __shared__ float red1[4], red2[4];
  __shared__ float tile[32][33];
  const int bid = blockIdx.x;
  const int tid = threadIdx.x;
  if (bid < ROWS) {
    // ---- LayerNorm + cast (row = bid) ----
    const float4* xr = (const float4*)(x + (size_t)bid * DIM);
    float4 v = xr[tid];
    float s1 = v.x + v.y + v.z + v.w;
    float s2 = v.x * v.x + v.y * v.y + v.z * v.z + v.w * v.w;
#pragma unroll
    for (int d = 32; d > 0; d >>= 1) {
      s1 += __shfl_xor(s1, d);
      s2 += __shfl_xor(s2, d);
    }
    const int wave = tid >> 6, lane = tid & 63;
    if (lane == 0) { red1[wave] = s1; red2[wave] = s2; }
    __syncthreads();
    s1 = red1[0] + red1[1] + red1[2] + red1[3];
    s2 = red2[0] + red2[1] + red2[2] + red2[3];
    const float mean = s1 * (1.0f / DIM);
    const float var = s2 * (1.0f / DIM) - mean * mean;
    const float rstd = rsqrtf(var + 1e-5f);
    float4 g = ((const float4*)gamma)[tid];
    float4 b = ((const float4*)beta)[tid];
    bf16x4 o;
    o[0] = (__bf16)((v.x - mean) * rstd * g.x + b.x);
    o[1] = (__bf16)((v.y - mean) * rstd * g.y + b.y);
    o[2] = (__bf16)((v.z - mean) * rstd * g.z + b.z);
    o[3] = (__bf16)((v.w - mean) * rstd * g.w + b.w);
    *(bf16x4*)(xnb + (size_t)bid * DIM + tid * 4) = o;
  } else {
    // ---- transpose + cast (K x N fp32 -> N x K bf16), 32x32 tiles ----
    const int id2 = bid - ROWS;       // 0..4095
    int bx = id2 & 127;               // 0..127
    const int by = id2 >> 7;          // 0..31
    const int tx = tid & 31, ty = tid >> 5;  // ty 0..7
    const float* in;
    __bf16* out;
    int cols;
    if (bx < 96) {
      in = wq; out = qT; cols = NQKV;
    } else {
      in = wo; out = oT; cols = DIM; bx -= 96;
    }
    const int c0 = bx * 32, r0 = by * 32;
#pragma unroll
    for (int rr = ty; rr < 32; rr += 8)
      tile[rr][tx] = in[(size_t)(r0 + rr) * cols + c0 + tx];
    __syncthreads();
#pragma unroll
    for (int rr = ty; rr < 32; rr += 8)
      out[(size_t)(c0 + rr) * DIM + r0 + tx] = (__bf16)tile[tx][rr];
  }
}

// ---- 256x128 MFMA GEMM, 3-buffer counted-vmcnt pipeline (1 barrier/K-tile) ----
// ROUND-6/9 PROVEN: 89.5 us, MfmaUtil 22%, FETCH ~= ideal 49 MB, 0 conflicts.
// 2D grid (Mtiles, Ntiles), x = M fastest. Locality/scheduling/occupancy axes
// all tested (rounds 7,8,10): this is the structure's local optimum.
template <int MODE>
__global__ __launch_bounds__(512, 1) void gemmP(
    const __bf16* __restrict__ A, const __bf16* __restrict__ Bt, const int K,
    const int N, float* __restrict__ Cout, __bf16* __restrict__ qb,
    __bf16* __restrict__ kb, __bf16* __restrict__ vtb) {
  __shared__ __bf16 As[3][2][128 * 64];  // [buf][half][lr][64]
  __shared__ __bf16 Bs[3][128 * 64];     // [buf][lr][64]
  const int tid = threadIdx.x;
  const int wave = tid >> 6, lane = tid & 63;
  const int quad = lane >> 4, l16 = lane & 15;
  const int wm = wave >> 2, wn = wave & 3;

  const size_t tileM = (size_t)blockIdx.x * 256;
  const size_t tileN = (size_t)blockIdx.y * 128;
  const int sel = (MODE == 1) ? (int)(tileN >> 10) : 0;  // 0=q 1=k 2=v
  const bool vmode = (MODE == 1) && (sel == 2);

  f32x4 acc[8][2];
#pragma unroll
  for (int a = 0; a < 8; ++a)
#pragma unroll
    for (int b = 0; b < 2; ++b) acc[a][b] = (f32x4){0.f, 0.f, 0.f, 0.f};

  const __bf16* Abase = A + tileM * (size_t)K;
  const __bf16* Bbase = Bt + tileN * (size_t)K;

  const int slr = tid >> 3, sc = tid & 7;
  const int scol = (sc ^ (slr & 7)) << 3;  // pre-swizzled source col (elems)

  auto stageA = [&](int buf, int h, int kt) {
    const size_t col = (size_t)(kt << 6) + scol;
#pragma unroll
    for (int p = 0; p < 2; ++p) {
      const int gr = p * 128 + h * 64 + slr;
      const int lr = p * 64 + slr;
      gload16(Abase + (size_t)gr * K + col, &As[buf][h][lr * 64 + sc * 8]);
    }
  };
  auto stageB = [&](int buf, int kt) {
    const size_t col = (size_t)(kt << 6) + scol;
#pragma unroll
    for (int p = 0; p < 2; ++p) {
      const int lr = p * 64 + slr;
      gload16(Bbase + (size_t)lr * K + col, &Bs[buf][lr * 64 + sc * 8]);
    }
  };
  auto stageTile = [&](int buf, int kt) {
    stageA(buf, 0, kt);
    stageB(buf, kt);
    stageA(buf, 1, kt);
  };

  const int rpc = quad ^ (l16 & 7);
  auto ldA = [&](int buf, int mt, int ks) -> bf16x8 {
    const int lr = wm * 64 + (mt & 3) * 16 + l16;
    return *(const bf16x8*)&As[buf][mt >> 2][lr * 64 + ((rpc ^ (ks << 2)) << 3)];
  };
  auto ldB = [&](int buf, int nt, int ks) -> bf16x8 {
    const int lr = wn * 32 + nt * 16 + l16;
    return *(const bf16x8*)&Bs[buf][lr * 64 + ((rpc ^ (ks << 2)) << 3)];
  };

  auto cluster = [&](const bf16x8* af, bf16x8 bf0, bf16x8 bf1, int mb) {
    __builtin_amdgcn_s_setprio(1);
    if (vmode) {
#pragma unroll
      for (int mt = 0; mt < 4; ++mt) {
        acc[mb + mt][0] = __builtin_amdgcn_mfma_f32_16x16x32_bf16(
            af[mt], bf0, acc[mb + mt][0], 0, 0, 0);
        acc[mb + mt][1] = __builtin_amdgcn_mfma_f32_16x16x32_bf16(
            af[mt], bf1, acc[mb + mt][1], 0, 0, 0);
      }
    } else {
#pragma unroll
      for (int mt = 0; mt < 4; ++mt) {
        acc[mb + mt][0] = __builtin_amdgcn_mfma_f32_16x16x32_bf16(
            bf0, af[mt], acc[mb + mt][0], 0, 0, 0);
        acc[mb + mt][1] = __builtin_amdgcn_mfma_f32_16x16x32_bf16(
            bf1, af[mt], acc[mb + mt][1], 0, 0, 0);
      }
    }
    __builtin_amdgcn_s_setprio(0);
  };

  // prologue: 2 tiles in flight
  stageTile(0, 0);
  stageTile(1, 1);

  const int NT = K >> 6;  // 16
  int bufc = 0;           // compute buffer, rotates 0,1,2
  bf16x8 af[4], b00, b01, b10, b11;

  for (int t = 0; t < NT; ++t) {
    if (t < NT - 1)
      asm volatile("s_waitcnt vmcnt(6)" ::: "memory");
    else
      asm volatile("s_waitcnt vmcnt(0)" ::: "memory");
    __builtin_amdgcn_s_barrier();
    asm volatile("" ::: "memory");
    __builtin_amdgcn_sched_barrier(0);

    if (t + 2 < NT) {
      const int sb = bufc + 2 >= 3 ? bufc - 1 : bufc + 2;  // (bufc+2)%3
      stageTile(sb, t + 2);
    }

    // ---- 4 compute phases: (mt0-3,ks0) (mt0-3,ks1) (mt4-7,ks0) (mt4-7,ks1)
#pragma unroll
    for (int mt = 0; mt < 4; ++mt) af[mt] = ldA(bufc, mt, 0);
    b00 = ldB(bufc, 0, 0);
    b01 = ldB(bufc, 1, 0);
    cluster(af, b00, b01, 0);
#pragma unroll
    for (int mt = 0; mt < 4; ++mt) af[mt] = ldA(bufc, mt, 1);
    b10 = ldB(bufc, 0, 1);
    b11 = ldB(bufc, 1, 1);
    cluster(af, b10, b11, 0);
#pragma unroll
    for (int mt = 0; mt < 4; ++mt) af[mt] = ldA(bufc, 4 + mt, 0);
    cluster(af, b00, b01, 4);
#pragma unroll
    for (int mt = 0; mt < 4; ++mt) af[mt] = ldA(bufc, 4 + mt, 1);
    cluster(af, b10, b11, 4);

    bufc = bufc == 2 ? 0 : bufc + 1;
  }

  // ---------------- epilogue (mapping proven rounds 1/4/6) ----------------
  if (MODE == 0) {
#pragma unroll
    for (int mt = 0; mt < 8; ++mt) {
      const size_t m = tileM + wm * 128 + mt * 16 + l16;
#pragma unroll
      for (int nt = 0; nt < 2; ++nt) {
        const size_t n0 = tileN + wn * 32 + nt * 16 + quad * 4;
        *(f32x4*)&Cout[m * (size_t)N + n0] = acc[mt][nt];
      }
    }
  } else if (sel < 2) {
    __bf16* dst = (sel == 0) ? qb : kb;
#pragma unroll
    for (int mt = 0; mt < 8; ++mt) {
      const size_t m = tileM + wm * 128 + mt * 16 + l16;
      const int b = (int)(m >> 11), seq = (int)(m & 2047);
#pragma unroll
      for (int nt = 0; nt < 2; ++nt) {
        const int c = (int)(tileN & 1023) + wn * 32 + nt * 16 + quad * 4;
        const int head = c >> 6, dh = c & 63;
        bf16x4 pk;
#pragma unroll
        for (int r = 0; r < 4; ++r) pk[r] = (__bf16)acc[mt][nt][r];
        *(bf16x4*)&dst[(((size_t)b * HEADS + head) * SEQ + seq) * DH + dh] = pk;
      }
    }
  } else {
#pragma unroll
    for (int nt = 0; nt < 2; ++nt) {
      const int c = (int)(tileN & 1023) + wn * 32 + nt * 16 + l16;
      const int head = c >> 6, dh = c & 63;
#pragma unroll
      for (int mt = 0; mt < 8; ++mt) {
        const size_t m0 = tileM + wm * 128 + mt * 16 + quad * 4;
        const int b = (int)(m0 >> 11), seq = (int)(m0 & 2047);
        bf16x4 pk;
#pragma unroll
        for (int r = 0; r < 4; ++r) pk[r] = (__bf16)acc[mt][nt][r];
        *(bf16x4*)&vtb[(((size_t)b * HEADS + head) * DH + dh) * SEQ + seq] = pk;
      }
    }
  }
}

// ---------------- flash-style causal attention, 128-row q-tiles ----------------
// NEW: QBLK=128, 4 waves x 32 q-rows (two 16-row groups qg). K/V fragments are
// wave-invariant AND qg-invariant -> read ONCE (8+8 ds_read_b128) and reused
// for 2x the MFMAs: per-q-row K/V LDS reads and staging traffic HALVE vs the
// 64-row version (the 4x cross-wave amplification was ~53 us of LDS time).
// grid (64 bh, 8): block pairs 128-row q-tiles by and 15-by -> P0+P1 = 34
// kv-iters for every block (perfect balance). 512 blocks = 2/CU, 8 waves/CU;
// prefetch-1-tile double-buffer covers staging latency (~1000 cyc compute/iter).
__global__ __launch_bounds__(256, 2) void attn_kernel(
    const __bf16* __restrict__ qb, const __bf16* __restrict__ kb,
    const __bf16* __restrict__ vtb, __bf16* __restrict__ ob) {
  const int bh = blockIdx.x;
  const int by = blockIdx.y;  // 0..7
  const int tid = threadIdx.x;
  const int wave = tid >> 6, lane = tid & 63;
  const int quad = lane >> 4, l16 = lane & 15;

  __shared__ __bf16 Ks[2][64 * 64];     // [kv][dh], XOR-swizzled
  __shared__ __bf16 Vs[2][64 * 64];     // [dh][kv], XOR-swizzled
  __shared__ __bf16 Ps[4][2][16 * 36];  // per-wave, per-qg P^T chunk

  const __bf16* kg = kb + (size_t)bh * SEQ * DH;
  const __bf16* vg = vtb + (size_t)bh * DH * SEQ;

  const int i1 = by, i2 = 15 - by;  // 128-row q-tile indices
  const int P0 = 2 * i1 + 2;        // phase-0 kv-iters
  const int T = P0 + 2 * i2 + 2;    // 34 total

  const int kr = lane >> 3, kc = lane & 7;

  auto stage = [&](int buf, int j) {
#pragma unroll
    for (int p = 0; p < 2; ++p) {
      const int rbase = wave * 16 + p * 8;
      const int row = rbase + kr;
      gload16(kg + (size_t)(j * 64 + row) * DH + ((kc ^ (row & 7)) << 3),
              &Ks[buf][rbase * 64]);
      gload16(vg + (size_t)row * SEQ + j * 64 + ((kc ^ (row & 7)) << 3),
              &Vs[buf][rbase * 64]);
    }
  };

  const float QSCALE = 0.125f * 1.44269504088896f;
  bf16x8 qf[2][2];  // [qg][ks]
  auto load_q = [&](int i) {
#pragma unroll
    for (int qg = 0; qg < 2; ++qg) {
      const __bf16* qbase =
          qb + ((size_t)bh * SEQ + (size_t)i * 128 + wave * 32 + qg * 16) * DH;
#pragma unroll
      for (int ks = 0; ks < 2; ++ks) {
        bf16x8 v = *(const bf16x8*)(qbase + l16 * DH + ks * 32 + quad * 8);
#pragma unroll
        for (int e = 0; e < 8; ++e) v[e] = (__bf16)((float)v[e] * QSCALE);
        qf[qg][ks] = v;
      }
    }
  };

  float m_i[2], l_i[2];   // per qg; l is LANE-PARTIAL (reduced at epilogue)
  f32x4 o_acc[2][4];      // [qg][md]
  auto reset_state = [&]() {
#pragma unroll
    for (int qg = 0; qg < 2; ++qg) {
      m_i[qg] = -1e30f;
      l_i[qg] = 0.f;
#pragma unroll
      for (int md = 0; md < 4; ++md) o_acc[qg][md] = (f32x4){0.f, 0.f, 0.f, 0.f};
    }
  };
  const int b_out = bh >> 4, h_out = bh & 15;
  auto epilogue = [&](int i) {
#pragma unroll
    for (int qg = 0; qg < 2; ++qg) {
      float lsum = l_i[qg];
      lsum += __shfl_xor(lsum, 16);
      lsum += __shfl_xor(lsum, 32);
      const float inv = __builtin_amdgcn_rcpf(lsum);
      const int seq = i * 128 + wave * 32 + qg * 16 + l16;
      __bf16* dst = ob + ((size_t)b_out * SEQ + seq) * DIM + h_out * DH;
#pragma unroll
      for (int md = 0; md < 4; ++md) {
        bf16x4 pk;
#pragma unroll
        for (int r = 0; r < 4; ++r) pk[r] = (__bf16)(o_acc[qg][md][r] * inv);
        *(bf16x4*)(dst + md * 16 + quad * 4) = pk;
      }
    }
  };

  load_q(i1);
  reset_state();
  stage(0, 0);

  for (int t = 0; t < T; ++t) {
    __syncthreads();  // staging for t complete; prev reads of this buf done
    if (t + 1 < T) {
      const int jn = (t + 1 < P0) ? (t + 1) : (t + 1 - P0);
      stage((t + 1) & 1, jn);
    }
    const int buf = t & 1;
    const bool ph0 = (t < P0);
    const int i = ph0 ? i1 : i2;
    const int j = ph0 ? t : t - P0;

    // K fragments once -> reused for both qg (the economy lever)
    bf16x8 kfr[4][2];
#pragma unroll
    for (int nt = 0; nt < 4; ++nt)
#pragma unroll
      for (int ks = 0; ks < 2; ++ks)
        kfr[nt][ks] = *(const bf16x8*)&Ks[buf][(nt * 16 + l16) * 64 +
                                              (((ks * 4 + quad) ^ (l16 & 7)) << 3)];

    // S^T = K Q^T per qg: rows(quad*4+r)=kv, cols(l16)=q-row
    f32x4 sa2[2][4];
#pragma unroll
    for (int qg = 0; qg < 2; ++qg)
#pragma unroll
      for (int nt = 0; nt < 4; ++nt) sa2[qg][nt] = (f32x4){0.f, 0.f, 0.f, 0.f};
    __builtin_amdgcn_s_setprio(1);
#pragma unroll
    for (int qg = 0; qg < 2; ++qg)
#pragma unroll
      for (int nt = 0; nt < 4; ++nt)
#pragma unroll
        for (int ks = 0; ks < 2; ++ks)
          sa2[qg][nt] = __builtin_amdgcn_mfma_f32_16x16x32_bf16(
              kfr[nt][ks], qf[qg][ks], sa2[qg][nt], 0, 0, 0);
    __builtin_amdgcn_s_setprio(0);

    // mask + online softmax (T13 defer-max) per qg
#pragma unroll
    for (int qg = 0; qg < 2; ++qg) {
      const int qrow0 = i * 128 + wave * 32 + qg * 16;  // wave-uniform
      if (j * 64 + 63 > qrow0) {                        // any masking needed?
        const int qr = qrow0 + l16;
#pragma unroll
        for (int nt = 0; nt < 4; ++nt)
#pragma unroll
          for (int r = 0; r < 4; ++r) {
            const int kv = j * 64 + nt * 16 + quad * 4 + r;
            if (kv > qr) sa2[qg][nt][r] = -1e30f;
          }
      }
      float mx = -1e30f;
#pragma unroll
      for (int nt = 0; nt < 4; ++nt) {
        const float a0 = fmaxf(fmaxf(sa2[qg][nt][0], sa2[qg][nt][1]), sa2[qg][nt][2]);
        mx = fmaxf(mx, fmaxf(a0, sa2[qg][nt][3]));
      }
      mx = fmaxf(mx, __shfl_xor(mx, 16));
      mx = fmaxf(mx, __shfl_xor(mx, 32));
      if (__all(mx - m_i[qg] <= 8.f)) {
        float rs = 0.f;
#pragma unroll
        for (int nt = 0; nt < 4; ++nt)
#pragma unroll
          for (int r = 0; r < 4; ++r) {
            const float p = fast_exp2(sa2[qg][nt][r] - m_i[qg]);
            sa2[qg][nt][r] = p;
            rs += p;
          }
        l_i[qg] += rs;
      } else {
        const float mnew = fmaxf(m_i[qg], mx);
        const float alpha = fast_exp2(m_i[qg] - mnew);
        m_i[qg] = mnew;
        float rs = 0.f;
#pragma unroll
        for (int nt = 0; nt < 4; ++nt)
#pragma unroll
          for (int r = 0; r < 4; ++r) {
            const float p = fast_exp2(sa2[qg][nt][r] - mnew);
            sa2[qg][nt][r] = p;
            rs += p;
          }
        l_i[qg] = l_i[qg] * alpha + rs;
#pragma unroll
        for (int md = 0; md < 4; ++md)
#pragma unroll
          for (int r = 0; r < 4; ++r) o_acc[qg][md][r] *= alpha;
      }
    }

    // O^T += V^T P^T: V fragments read once per (c,md), feed both qg
#pragma unroll
    for (int c = 0; c < 2; ++c) {
#pragma unroll
      for (int qg = 0; qg < 2; ++qg)
#pragma unroll
        for (int ntl = 0; ntl < 2; ++ntl) {
          const int nt = c * 2 + ntl;
          bf16x4 pk;
#pragma unroll
          for (int r = 0; r < 4; ++r) pk[r] = (__bf16)sa2[qg][nt][r];
          *(bf16x4*)&Ps[wave][qg][l16 * 36 + ntl * 16 + quad * 4] = pk;
        }
      bf16x8 pf0 = *(const bf16x8*)&Ps[wave][0][l16 * 36 + quad * 8];
      bf16x8 pf1 = *(const bf16x8*)&Ps[wave][1][l16 * 36 + quad * 8];
      __builtin_amdgcn_s_setprio(1);
#pragma unroll
      for (int md = 0; md < 4; ++md) {
        bf16x8 vf = *(const bf16x8*)&Vs[buf][(md * 16 + l16) * 64 +
                                            (((c * 4 + quad) ^ (l16 & 7)) << 3)];
        o_acc[0][md] =
            __builtin_amdgcn_mfma_f32_16x16x32_bf16(vf, pf0, o_acc[0][md], 0, 0, 0);
        o_acc[1][md] =
            __builtin_amdgcn_mfma_f32_16x16x32_bf16(vf, pf1, o_acc[1][md], 0, 0, 0);
      }
      __builtin_amdgcn_s_setprio(0);
    }

    if (t == P0 - 1) {  // phase 0 done: flush, switch to q-tile i2
      epilogue(i1);
      reset_state();
      load_q(i2);
    }
  }
  epilogue(i2);
}

// ---------------- launch ----------------
extern "C" void kernel_launch(void* const* d_in, const int* in_sizes, int n_in,
                              void* d_out, int out_size, void* d_ws, size_t ws_size,
                              hipStream_t stream) {
  const float* x = (const float*)d_in[0];
  const float* gamma = (const float*)d_in[1];
  const float* beta = (const float*)d_in[2];
  const float* w_qkv = (const float*)d_in[3];
  const float* w_out = (const float*)d_in[4];
  float* out = (float*)d_out;

  char* ws = (char*)d_ws;
  const size_t MB = 1024 * 1024;
  __bf16* xnb = (__bf16*)ws;                    // 16 MiB (dead after QKV gemm)
  __bf16* wqkvT = (__bf16*)(ws + 16 * MB);      // 6 MiB
  __bf16* woutT = (__bf16*)(ws + 24 * MB);      // 2 MiB
  __bf16* qbuf = (__bf16*)(ws + 32 * MB);       // 16 MiB
  __bf16* kbuf = (__bf16*)(ws + 48 * MB);       // 16 MiB
  __bf16* vtbuf = (__bf16*)(ws + 64 * MB);      // 16 MiB
  __bf16* attnb = xnb;                          // alias: xn dead by then

  ln_tc<<<ROWS + 4096, 256, 0, stream>>>(x, gamma, beta, xnb, w_qkv, w_out,
                                         wqkvT, woutT);
  gemmP<1><<<dim3(ROWS / 256, NQKV / 128), 512, 0, stream>>>(
      xnb, wqkvT, DIM, NQKV, nullptr, qbuf, kbuf, vtbuf);
  attn_kernel<<<dim3(BATCH * HEADS, 8), 256, 0, stream>>>(qbuf, kbuf, vtbuf, attnb);
  gemmP<0><<<dim3(ROWS / 256, DIM / 128), 512, 0, stream>>>(
      attnb, woutT, DIM, DIM, out, nullptr, nullptr, nullptr);
}

// Round 12
// 267.432 us; speedup vs baseline: 1.0426x; 1.0426x over previous
//
#include <hip/hip_runtime.h>
#include <hip/hip_bf16.h>

#define DIM 1024
#define HEADS 16
#define DH 64
#define SEQ 2048
#define BATCH 4
#define ROWS (BATCH * SEQ)   // 8192
#define NQKV (3 * DIM)       // 3072

typedef __attribute__((ext_vector_type(8))) __bf16 bf16x8;
typedef __attribute__((ext_vector_type(4))) __bf16 bf16x4;
typedef __attribute__((ext_vector_type(4))) float f32x4;

__device__ inline void gload16(const void* g, void* l) {
  __builtin_amdgcn_global_load_lds(
      (const __attribute__((address_space(1))) void*)g,
      (__attribute__((address_space(3))) void*)l, 16, 0, 0);
}

__device__ inline float fast_exp2(float x) {
#if __has_builtin(__builtin_amdgcn_exp2f)
  return __builtin_amdgcn_exp2f(x);  // raw v_exp_f32, no denorm guard
#else
  return exp2f(x);
#endif
}

// ------- fused LayerNorm (blocks 0..8191) + weight transpose (8192..12287) ----
__global__ __launch_bounds__(256) void ln_tc(
    const float* __restrict__ x, const float* __restrict__ gamma,
    const float* __restrict__ beta, __bf16* __restrict__ xnb,
    const float* __restrict__ wq, const float* __restrict__ wo,
    __bf16* __restrict__ qT, __bf16* __restrict__ oT) {
  __shared__ float red1[4], red2[4];
  __shared__ float tile[32][33];
  const int bid = blockIdx.x;
  const int tid = threadIdx.x;
  if (bid < ROWS) {
    // ---- LayerNorm + cast (row = bid) ----
    const float4* xr = (const float4*)(x + (size_t)bid * DIM);
    float4 v = xr[tid];
    float s1 = v.x + v.y + v.z + v.w;
    float s2 = v.x * v.x + v.y * v.y + v.z * v.z + v.w * v.w;
#pragma unroll
    for (int d = 32; d > 0; d >>= 1) {
      s1 += __shfl_xor(s1, d);
      s2 += __shfl_xor(s2, d);
    }
    const int wave = tid >> 6, lane = tid & 63;
    if (lane == 0) { red1[wave] = s1; red2[wave] = s2; }
    __syncthreads();
    s1 = red1[0] + red1[1] + red1[2] + red1[3];
    s2 = red2[0] + red2[1] + red2[2] + red2[3];
    const float mean = s1 * (1.0f / DIM);
    const float var = s2 * (1.0f / DIM) - mean * mean;
    const float rstd = rsqrtf(var + 1e-5f);
    float4 g = ((const float4*)gamma)[tid];
    float4 b = ((const float4*)beta)[tid];
    bf16x4 o;
    o[0] = (__bf16)((v.x - mean) * rstd * g.x + b.x);
    o[1] = (__bf16)((v.y - mean) * rstd * g.y + b.y);
    o[2] = (__bf16)((v.z - mean) * rstd * g.z + b.z);
    o[3] = (__bf16)((v.w - mean) * rstd * g.w + b.w);
    *(bf16x4*)(xnb + (size_t)bid * DIM + tid * 4) = o;
  } else {
    // ---- transpose + cast (K x N fp32 -> N x K bf16), 32x32 tiles ----
    const int id2 = bid - ROWS;       // 0..4095
    int bx = id2 & 127;               // 0..127
    const int by = id2 >> 7;          // 0..31
    const int tx = tid & 31, ty = tid >> 5;  // ty 0..7
    const float* in;
    __bf16* out;
    int cols;
    if (bx < 96) {
      in = wq; out = qT; cols = NQKV;
    } else {
      in = wo; out = oT; cols = DIM; bx -= 96;
    }
    const int c0 = bx * 32, r0 = by * 32;
#pragma unroll
    for (int rr = ty; rr < 32; rr += 8)
      tile[rr][tx] = in[(size_t)(r0 + rr) * cols + c0 + tx];
    __syncthreads();
#pragma unroll
    for (int rr = ty; rr < 32; rr += 8)
      out[(size_t)(c0 + rr) * DIM + r0 + tx] = (__bf16)tile[tx][rr];
  }
}

// ---- 256x128 MFMA GEMM, 3-buffer counted-vmcnt pipeline (1 barrier/K-tile) ----
// ROUND-6/9 PROVEN: 89.5 us, MfmaUtil 22%, FETCH ~= ideal 49 MB, 0 conflicts.
// 2D grid (Mtiles, Ntiles), x = M fastest. Locality/scheduling/occupancy axes
// all tested (rounds 7,8,10): this is the structure's local optimum.
template <int MODE>
__global__ __launch_bounds__(512, 1) void gemmP(
    const __bf16* __restrict__ A, const __bf16* __restrict__ Bt, const int K,
    const int N, float* __restrict__ Cout, __bf16* __restrict__ qb,
    __bf16* __restrict__ kb, __bf16* __restrict__ vtb) {
  __shared__ __bf16 As[3][2][128 * 64];  // [buf][half][lr][64]
  __shared__ __bf16 Bs[3][128 * 64];     // [buf][lr][64]
  const int tid = threadIdx.x;
  const int wave = tid >> 6, lane = tid & 63;
  const int quad = lane >> 4, l16 = lane & 15;
  const int wm = wave >> 2, wn = wave & 3;

  const size_t tileM = (size_t)blockIdx.x * 256;
  const size_t tileN = (size_t)blockIdx.y * 128;
  const int sel = (MODE == 1) ? (int)(tileN >> 10) : 0;  // 0=q 1=k 2=v
  const bool vmode = (MODE == 1) && (sel == 2);

  f32x4 acc[8][2];
#pragma unroll
  for (int a = 0; a < 8; ++a)
#pragma unroll
    for (int b = 0; b < 2; ++b) acc[a][b] = (f32x4){0.f, 0.f, 0.f, 0.f};

  const __bf16* Abase = A + tileM * (size_t)K;
  const __bf16* Bbase = Bt + tileN * (size_t)K;

  const int slr = tid >> 3, sc = tid & 7;
  const int scol = (sc ^ (slr & 7)) << 3;  // pre-swizzled source col (elems)

  auto stageA = [&](int buf, int h, int kt) {
    const size_t col = (size_t)(kt << 6) + scol;
#pragma unroll
    for (int p = 0; p < 2; ++p) {
      const int gr = p * 128 + h * 64 + slr;
      const int lr = p * 64 + slr;
      gload16(Abase + (size_t)gr * K + col, &As[buf][h][lr * 64 + sc * 8]);
    }
  };
  auto stageB = [&](int buf, int kt) {
    const size_t col = (size_t)(kt << 6) + scol;
#pragma unroll
    for (int p = 0; p < 2; ++p) {
      const int lr = p * 64 + slr;
      gload16(Bbase + (size_t)lr * K + col, &Bs[buf][lr * 64 + sc * 8]);
    }
  };
  auto stageTile = [&](int buf, int kt) {
    stageA(buf, 0, kt);
    stageB(buf, kt);
    stageA(buf, 1, kt);
  };

  const int rpc = quad ^ (l16 & 7);
  auto ldA = [&](int buf, int mt, int ks) -> bf16x8 {
    const int lr = wm * 64 + (mt & 3) * 16 + l16;
    return *(const bf16x8*)&As[buf][mt >> 2][lr * 64 + ((rpc ^ (ks << 2)) << 3)];
  };
  auto ldB = [&](int buf, int nt, int ks) -> bf16x8 {
    const int lr = wn * 32 + nt * 16 + l16;
    return *(const bf16x8*)&Bs[buf][lr * 64 + ((rpc ^ (ks << 2)) << 3)];
  };

  auto cluster = [&](const bf16x8* af, bf16x8 bf0, bf16x8 bf1, int mb) {
    __builtin_amdgcn_s_setprio(1);
    if (vmode) {
#pragma unroll
      for (int mt = 0; mt < 4; ++mt) {
        acc[mb + mt][0] = __builtin_amdgcn_mfma_f32_16x16x32_bf16(
            af[mt], bf0, acc[mb + mt][0], 0, 0, 0);
        acc[mb + mt][1] = __builtin_amdgcn_mfma_f32_16x16x32_bf16(
            af[mt], bf1, acc[mb + mt][1], 0, 0, 0);
      }
    } else {
#pragma unroll
      for (int mt = 0; mt < 4; ++mt) {
        acc[mb + mt][0] = __builtin_amdgcn_mfma_f32_16x16x32_bf16(
            bf0, af[mt], acc[mb + mt][0], 0, 0, 0);
        acc[mb + mt][1] = __builtin_amdgcn_mfma_f32_16x16x32_bf16(
            bf1, af[mt], acc[mb + mt][1], 0, 0, 0);
      }
    }
    __builtin_amdgcn_s_setprio(0);
  };

  // prologue: 2 tiles in flight
  stageTile(0, 0);
  stageTile(1, 1);

  const int NT = K >> 6;  // 16
  int bufc = 0;           // compute buffer, rotates 0,1,2
  bf16x8 af[4], b00, b01, b10, b11;

  for (int t = 0; t < NT; ++t) {
    if (t < NT - 1)
      asm volatile("s_waitcnt vmcnt(6)" ::: "memory");
    else
      asm volatile("s_waitcnt vmcnt(0)" ::: "memory");
    __builtin_amdgcn_s_barrier();
    asm volatile("" ::: "memory");
    __builtin_amdgcn_sched_barrier(0);

    if (t + 2 < NT) {
      const int sb = bufc + 2 >= 3 ? bufc - 1 : bufc + 2;  // (bufc+2)%3
      stageTile(sb, t + 2);
    }

    // ---- 4 compute phases: (mt0-3,ks0) (mt0-3,ks1) (mt4-7,ks0) (mt4-7,ks1)
#pragma unroll
    for (int mt = 0; mt < 4; ++mt) af[mt] = ldA(bufc, mt, 0);
    b00 = ldB(bufc, 0, 0);
    b01 = ldB(bufc, 1, 0);
    cluster(af, b00, b01, 0);
#pragma unroll
    for (int mt = 0; mt < 4; ++mt) af[mt] = ldA(bufc, mt, 1);
    b10 = ldB(bufc, 0, 1);
    b11 = ldB(bufc, 1, 1);
    cluster(af, b10, b11, 0);
#pragma unroll
    for (int mt = 0; mt < 4; ++mt) af[mt] = ldA(bufc, 4 + mt, 0);
    cluster(af, b00, b01, 4);
#pragma unroll
    for (int mt = 0; mt < 4; ++mt) af[mt] = ldA(bufc, 4 + mt, 1);
    cluster(af, b10, b11, 4);

    bufc = bufc == 2 ? 0 : bufc + 1;
  }

  // ---------------- epilogue (mapping proven rounds 1/4/6) ----------------
  if (MODE == 0) {
#pragma unroll
    for (int mt = 0; mt < 8; ++mt) {
      const size_t m = tileM + wm * 128 + mt * 16 + l16;
#pragma unroll
      for (int nt = 0; nt < 2; ++nt) {
        const size_t n0 = tileN + wn * 32 + nt * 16 + quad * 4;
        *(f32x4*)&Cout[m * (size_t)N + n0] = acc[mt][nt];
      }
    }
  } else if (sel < 2) {
    __bf16* dst = (sel == 0) ? qb : kb;
#pragma unroll
    for (int mt = 0; mt < 8; ++mt) {
      const size_t m = tileM + wm * 128 + mt * 16 + l16;
      const int b = (int)(m >> 11), seq = (int)(m & 2047);
#pragma unroll
      for (int nt = 0; nt < 2; ++nt) {
        const int c = (int)(tileN & 1023) + wn * 32 + nt * 16 + quad * 4;
        const int head = c >> 6, dh = c & 63;
        bf16x4 pk;
#pragma unroll
        for (int r = 0; r < 4; ++r) pk[r] = (__bf16)acc[mt][nt][r];
        *(bf16x4*)&dst[(((size_t)b * HEADS + head) * SEQ + seq) * DH + dh] = pk;
      }
    }
  } else {
#pragma unroll
    for (int nt = 0; nt < 2; ++nt) {
      const int c = (int)(tileN & 1023) + wn * 32 + nt * 16 + l16;
      const int head = c >> 6, dh = c & 63;
#pragma unroll
      for (int mt = 0; mt < 8; ++mt) {
        const size_t m0 = tileM + wm * 128 + mt * 16 + quad * 4;
        const int b = (int)(m0 >> 11), seq = (int)(m0 & 2047);
        bf16x4 pk;
#pragma unroll
        for (int r = 0; r < 4; ++r) pk[r] = (__bf16)acc[mt][nt][r];
        *(bf16x4*)&vtb[(((size_t)b * HEADS + head) * DH + dh) * SEQ + seq] = pk;
      }
    }
  }
}

// ---------------- flash-style causal attention, 64x64 tiles ----------------
// ROUND-9 PROVEN (~85 us within the 271.3 total). grid (BATCH*HEADS, 16):
// all 16 blocks of a head on ONE XCD. Block y handles q-tiles y and 31-y:
// 33 kv-iters for every block. 1024 blocks = 4/CU -> 16 waves/CU.
// T13 defer-max + max3 + T5 setprio (all individually ~null, kept: harmless).
__global__ __launch_bounds__(256, 4) void attn_kernel(
    const __bf16* __restrict__ qb, const __bf16* __restrict__ kb,
    const __bf16* __restrict__ vtb, __bf16* __restrict__ ob) {
  const int bh = blockIdx.x;
  const int by = blockIdx.y;  // 0..15
  const int tid = threadIdx.x;
  const int wave = tid >> 6, lane = tid & 63;
  const int quad = lane >> 4, l16 = lane & 15;

  __shared__ __bf16 Ks[2][64 * 64];  // [kv][dh], 8 chunks/row, XOR-swizzled
  __shared__ __bf16 Vs[2][64 * 64];  // [dh][kv], 8 chunks/row, XOR-swizzled
  __shared__ __bf16 Ps[4][16 * 36];  // per-wave P^T chunk: 16 qrows x 32 kv (+pad)

  const __bf16* kg = kb + (size_t)bh * SEQ * DH;
  const __bf16* vg = vtb + (size_t)bh * DH * SEQ;

  const int i1 = by, i2 = 31 - by;
  const int T = 33;

  const int kr = lane >> 3, kc = lane & 7;  // stage: 8 rows x 8 chunks per instr

  auto stage = [&](int buf, int j) {
#pragma unroll
    for (int p = 0; p < 2; ++p) {
      const int rbase = wave * 16 + p * 8;
      const int row = rbase + kr;
      gload16(kg + (size_t)(j * 64 + row) * DH + ((kc ^ (row & 7)) << 3),
              &Ks[buf][rbase * 64]);
      gload16(vg + (size_t)row * SEQ + j * 64 + ((kc ^ (row & 7)) << 3),
              &Vs[buf][rbase * 64]);
    }
  };

  // Q as B-operand fragments, pre-scaled by dh^-0.5 * log2(e) (exp2 domain)
  const float QSCALE = 0.125f * 1.44269504088896f;
  bf16x8 qf[2];
  auto load_q = [&](int i) {
    const __bf16* qbase = qb + ((size_t)bh * SEQ + (size_t)i * 64 + wave * 16) * DH;
#pragma unroll
    for (int ks = 0; ks < 2; ++ks) {
      bf16x8 v = *(const bf16x8*)(qbase + l16 * DH + ks * 32 + quad * 8);
#pragma unroll
      for (int e = 0; e < 8; ++e) v[e] = (__bf16)((float)v[e] * QSCALE);
      qf[ks] = v;
    }
  };

  float m_i, l_i;     // one q-row per lane; l is LANE-PARTIAL (reduced at epilogue)
  f32x4 o_acc[4];     // O^T: [md dh-frag], col=l16=qrow
  auto reset_state = [&]() {
    m_i = -1e30f;
    l_i = 0.f;
#pragma unroll
    for (int md = 0; md < 4; ++md) o_acc[md] = (f32x4){0.f, 0.f, 0.f, 0.f};
  };
  const int b_out = bh >> 4, h_out = bh & 15;
  auto epilogue = [&](int i) {
    float lsum = l_i;  // cross-quad all-reduce (deferred from the k-loop)
    lsum += __shfl_xor(lsum, 16);
    lsum += __shfl_xor(lsum, 32);
    const float inv = __builtin_amdgcn_rcpf(lsum);
    const int seq = i * 64 + wave * 16 + l16;
    __bf16* dst = ob + ((size_t)b_out * SEQ + seq) * DIM + h_out * DH;
#pragma unroll
    for (int md = 0; md < 4; ++md) {
      bf16x4 pk;
#pragma unroll
      for (int r = 0; r < 4; ++r) pk[r] = (__bf16)(o_acc[md][r] * inv);
      *(bf16x4*)(dst + md * 16 + quad * 4) = pk;
    }
  };

  load_q(i1);
  reset_state();
  stage(0, 0);

  for (int t = 0; t < T; ++t) {
    __syncthreads();  // staging for t complete; prev reads of this buf done
    if (t + 1 < T) {
      const int jn = (t + 1 <= by) ? (t + 1) : (t - by);
      stage((t + 1) & 1, jn);
    }
    const int buf = t & 1;
    const int i = (t <= by) ? i1 : i2;
    const int j = (t <= by) ? t : (t - by - 1);
    const bool diag = (j == i);

    // S^T = K Q^T : rows(quad*4+r)=kv 0..63, cols(l16)=q-row (wave's 16 rows)
    f32x4 sa[4];
#pragma unroll
    for (int nt = 0; nt < 4; ++nt) sa[nt] = (f32x4){0.f, 0.f, 0.f, 0.f};
    __builtin_amdgcn_s_setprio(1);
#pragma unroll
    for (int nt = 0; nt < 4; ++nt)
#pragma unroll
      for (int ks = 0; ks < 2; ++ks) {
        bf16x8 kf = *(const bf16x8*)&Ks[buf][(nt * 16 + l16) * 64 +
                                            (((ks * 4 + quad) ^ (l16 & 7)) << 3)];
        sa[nt] = __builtin_amdgcn_mfma_f32_16x16x32_bf16(kf, qf[ks], sa[nt], 0, 0, 0);
      }
    __builtin_amdgcn_s_setprio(0);

    if (diag) {
      const int qrl = wave * 16 + l16;  // local q-row 0..63
#pragma unroll
      for (int nt = 0; nt < 4; ++nt)
#pragma unroll
        for (int r = 0; r < 4; ++r) {
          const int kvl = nt * 16 + quad * 4 + r;
          if (kvl > qrl) sa[nt][r] = -1e30f;
        }
    }

    // online softmax with T13 defer-max; only MAX needs cross-quad reduce
    {
      float mx = -1e30f;
#pragma unroll
      for (int nt = 0; nt < 4; ++nt) {
        const float a0 = fmaxf(fmaxf(sa[nt][0], sa[nt][1]), sa[nt][2]);  // v_max3
        mx = fmaxf(mx, fmaxf(a0, sa[nt][3]));
      }
      mx = fmaxf(mx, __shfl_xor(mx, 16));
      mx = fmaxf(mx, __shfl_xor(mx, 32));
      if (__all(mx - m_i <= 8.f)) {
        // deferred: alpha == 2^0 == 1 exactly -> skip l/o rescale entirely
        float rs = 0.f;
#pragma unroll
        for (int nt = 0; nt < 4; ++nt)
#pragma unroll
          for (int r = 0; r < 4; ++r) {
            const float p = fast_exp2(sa[nt][r] - m_i);
            sa[nt][r] = p;
            rs += p;
          }
        l_i += rs;
      } else {
        const float mnew = fmaxf(m_i, mx);
        const float alpha = fast_exp2(m_i - mnew);
        m_i = mnew;
        float rs = 0.f;
#pragma unroll
        for (int nt = 0; nt < 4; ++nt)
#pragma unroll
          for (int r = 0; r < 4; ++r) {
            const float p = fast_exp2(sa[nt][r] - mnew);
            sa[nt][r] = p;
            rs += p;
          }
        l_i = l_i * alpha + rs;  // lane-partial; reduced at epilogue
#pragma unroll
        for (int md = 0; md < 4; ++md)
#pragma unroll
          for (int r = 0; r < 4; ++r) o_acc[md][r] *= alpha;
      }
    }

    // O^T += V^T P^T in 2 chunks of 32 kv; Ps wave-private (no barrier)
#pragma unroll
    for (int c = 0; c < 2; ++c) {
#pragma unroll
      for (int ntl = 0; ntl < 2; ++ntl) {
        const int nt = c * 2 + ntl;
        bf16x4 pk;
#pragma unroll
        for (int r = 0; r < 4; ++r) pk[r] = (__bf16)sa[nt][r];
        *(bf16x4*)&Ps[wave][l16 * 36 + ntl * 16 + quad * 4] = pk;
      }
      bf16x8 pf = *(const bf16x8*)&Ps[wave][l16 * 36 + quad * 8];
      __builtin_amdgcn_s_setprio(1);
#pragma unroll
      for (int md = 0; md < 4; ++md) {
        bf16x8 vf = *(const bf16x8*)&Vs[buf][(md * 16 + l16) * 64 +
                                            (((c * 4 + quad) ^ (l16 & 7)) << 3)];
        o_acc[md] = __builtin_amdgcn_mfma_f32_16x16x32_bf16(vf, pf, o_acc[md], 0, 0, 0);
      }
      __builtin_amdgcn_s_setprio(0);
    }

    if (t == by) {  // phase 0 done: flush, switch to q-tile i2
      epilogue(i1);
      reset_state();
      load_q(i2);
    }
  }
  epilogue(i2);
}

// ---------------- launch ----------------
extern "C" void kernel_launch(void* const* d_in, const int* in_sizes, int n_in,
                              void* d_out, int out_size, void* d_ws, size_t ws_size,
                              hipStream_t stream) {
  const float* x = (const float*)d_in[0];
  const float* gamma = (const float*)d_in[1];
  const float* beta = (const float*)d_in[2];
  const float* w_qkv = (const float*)d_in[3];
  const float* w_out = (const float*)d_in[4];
  float* out = (float*)d_out;

  char* ws = (char*)d_ws;
  const size_t MB = 1024 * 1024;
  __bf16* xnb = (__bf16*)ws;                    // 16 MiB (dead after QKV gemm)
  __bf16* wqkvT = (__bf16*)(ws + 16 * MB);      // 6 MiB
  __bf16* woutT = (__bf16*)(ws + 24 * MB);      // 2 MiB
  __bf16* qbuf = (__bf16*)(ws + 32 * MB);       // 16 MiB
  __bf16* kbuf = (__bf16*)(ws + 48 * MB);       // 16 MiB
  __bf16* vtbuf = (__bf16*)(ws + 64 * MB);      // 16 MiB
  __bf16* attnb = xnb;                          // alias: xn dead by then

  ln_tc<<<ROWS + 4096, 256, 0, stream>>>(x, gamma, beta, xnb, w_qkv, w_out,
                                         wqkvT, woutT);
  gemmP<1><<<dim3(ROWS / 256, NQKV / 128), 512, 0, stream>>>(
      xnb, wqkvT, DIM, NQKV, nullptr, qbuf, kbuf, vtbuf);
  attn_kernel<<<dim3(BATCH * HEADS, 16), 256, 0, stream>>>(qbuf, kbuf, vtbuf, attnb);
  gemmP<0><<<dim3(ROWS / 256, DIM / 128), 512, 0, stream>>>(
      attnb, woutT, DIM, DIM, out, nullptr, nullptr, nullptr);
}